// Round 18
// baseline (51.931 us; speedup 1.0000x reference)
//
#include <hip/hip_runtime.h>
#include <stdint.h>
#include <type_traits>

// DCN forward: B=4, H=128, W=128, G=8, C=32, K=8
// inputs      [B,H,W,G,C]   fp32
// deformables [B,H,W,G,K,2] fp32
// weights     [B,H,W,G,K]   fp32
// out         [B,H,W,G,C]   fp32
//
// R18 = R17 layout + 2 lanes/pixel (coord-math share of k-loop VALU drops
// 49% -> 35%: coord ~35 wave-insts/k is wave-uniform per PIXEL, so a wave
// holding 32 px amortizes it 2x better than 16 px; FMA & LDS totals are
// mapping-invariant). R14 proved the 2-lane mapping; R15 proved fma_mix;
// this composes them.
//  - 256 thr = 8x16 px tile, 2 lanes/px (16 ch each); window 16x25 cells
//    x 64 B (CUNITS=4) = 25.6 KB LDS.
//  - keeps: v_fma_mix_f32 asm, RH=4, coalesced staging, interior
//    mask-elision, unclamped-index == staging-clamp equivalence, exact f32
//    fallback (P~1e-4).

#define Bc 4
#define Hc 128
#define Wc 128
#define Gc 8
#define Kc 8
#define TH 8
#define TW 16
#define RH 4
#define WR 16             // window rows = TH + 2*RH
#define WN 25             // window cols (24 used + 1 pad col, odd)
#define NCELL (WR*WN)     // 400
#define CUNITS 4          // 16B units per cell (64 B, no pad)

typedef float    float4v __attribute__((ext_vector_type(4)));
typedef _Float16 half8v  __attribute__((ext_vector_type(8)));
typedef uint32_t uint4v  __attribute__((ext_vector_type(4)));

union PkU { half8v h; uint4v u; };

// acc += (f16 lo/hi of PK) * C   -- exact f32 fma, f16 converted exactly
#define FMA_MIX_LO(ACC, PK, C) \
    asm("v_fma_mix_f32 %0, %1, %2, %0 op_sel:[0,0,0] op_sel_hi:[1,0,0]" \
        : "+v"(ACC) : "v"(PK), "v"(C))
#define FMA_MIX_HI(ACC, PK, C) \
    asm("v_fma_mix_f32 %0, %1, %2, %0 op_sel:[1,0,0] op_sel_hi:[1,0,0]" \
        : "+v"(ACC) : "v"(PK), "v"(C))

__global__ __launch_bounds__(256, 6) void dcn_fwd(
    const float* __restrict__ inp,
    const float* __restrict__ def,
    const float* __restrict__ wts,
    float* __restrict__ out)
{
    const int tid = threadIdx.x;
    const int j   = tid & 1;       // lane owns channels 16j..16j+15 (2 units)
    const int px  = tid >> 1;      // 0..127 pixel in tile
    const int pw  = px & 15;
    const int ph  = px >> 4;

    // grid: wt(8), ht(16), g(8), b(4)
    const int blk = blockIdx.x;
    const int wt = blk & 7;
    const int ht = (blk >> 3) & 15;
    const int g  = (blk >> 7) & 7;
    const int b  = blk >> 10;

    const int h0 = ht * TH, w0 = wt * TW;
    const int row0 = h0 - RH, col0 = w0 - RH;   // window origin (may be <0)

    // global plane as float4 units: index = y*8192 + x*64 + u
    const float4v* gp4 = (const float4v*)((const char*)inp
        + ((size_t)b << 24) + ((size_t)g << 7));

    __shared__ uint4v tile[NCELL * CUNITS];   // 25600 B

    const int h = h0 + ph;
    const int w = w0 + pw;
    const int pg = ((b * Hc + h) * Wc + w) * Gc + g;

    // per-pixel def/wts (2 lanes load same addr; coalescer merges)
    const float4v d0 = *(const float4v*)(def + (size_t)pg * 16 + 0);
    const float4v d1 = *(const float4v*)(def + (size_t)pg * 16 + 4);
    const float4v d2 = *(const float4v*)(def + (size_t)pg * 16 + 8);
    const float4v d3 = *(const float4v*)(def + (size_t)pg * 16 + 12);
    const float4v q0 = *(const float4v*)(wts + (size_t)pg * 8 + 0);
    const float4v q1 = *(const float4v*)(wts + (size_t)pg * 8 + 4);

    // ---- stage 16x25 cell window as f16 (RTE): linear (cell,u2), coalesced ----
    // 400 cells x 4 units = 1600 writes; 7 rounds of 256 (last partial).
#pragma unroll
    for (int r = 0; r < 7; ++r) {
        const int idx = r * 256 + tid;
        if (idx < NCELL * CUNITS) {
            const int cell = idx >> 2;
            const int u2   = idx & 3;
            const int rr   = (cell * 2622) >> 16;    // exact cell/25, cell<400
            const int cc   = cell - rr * WN;
            const int gr   = min(max(row0 + rr, 0), Hc - 1);
            const int gc   = min(max(col0 + cc, 0), Wc - 1);
            const float4v* src = &gp4[gr * 8192 + gc * 64 + u2 * 2];
            const float4v a = src[0];
            const float4v c = src[1];
            PkU p;
            p.h = (half8v){(_Float16)a.x, (_Float16)a.y, (_Float16)a.z, (_Float16)a.w,
                           (_Float16)c.x, (_Float16)c.y, (_Float16)c.z, (_Float16)c.w};
            tile[(cell << 2) + u2] = p.u;
        }
    }
    __syncthreads();

    const float dxs[8] = {d0.x, d0.z, d1.x, d1.z, d2.x, d2.z, d3.x, d3.z};
    const float dys[8] = {d0.y, d0.w, d1.y, d1.w, d2.y, d2.w, d3.y, d3.w};
    const float wks[8] = {q0.x, q0.y, q0.z, q0.w, q1.x, q1.y, q1.z, q1.w};

    const float wf = (float)w;
    const float hf = (float)h;
    const int j2 = j * 2;          // first 16B unit owned by this lane

    float acc[16];
#pragma unroll
    for (int i = 0; i < 16; ++i) acc[i] = 0.f;

    auto kloop = [&](auto masked_t) {
        constexpr bool MASKED = decltype(masked_t)::value;
#pragma unroll
        for (int k = 0; k < Kc; ++k) {
            const float dx = dxs[k];
            const float dy = dys[k];
            const float wk = wks[k];

            const float x = dx + wf;
            const float y = dy + hf;

            // truncation toward zero, matching .astype(int32)
            const int fx = (int)x;
            const int fy = (int)y;

            const float wx1 = x - (float)fx;   // exact
            const float wy1 = y - (float)fy;
            const float wx0 = 1.0f - wx1;      // == cxf - x
            const float wy0 = 1.0f - wy1;

            const bool inh = (fabsf(dx) < 4.0f) & (fabsf(dy) < 4.0f);
            if (__builtin_expect(inh, 1)) {
                float ax0 = wx0, ax1 = wx1, ay0 = wy0, ay1 = wy1;
                if constexpr (MASKED) {
                    ax0 = ((uint32_t)fx       < (uint32_t)Wc) ? wx0 : 0.f;
                    ax1 = ((uint32_t)(fx + 1) < (uint32_t)Wc) ? wx1 : 0.f;
                    ay0 = ((uint32_t)fy       < (uint32_t)Hc) ? wy0 : 0.f;
                    ay1 = ((uint32_t)(fy + 1) < (uint32_t)Hc) ? wy1 : 0.f;
                }
                const float ay0k = wk * ay0;
                const float ay1k = wk * ay1;
                const float cw[4] = {ay0k * ax0, ay0k * ax1,
                                     ay1k * ax0, ay1k * ax1};

                // unclamped fx,fy valid in-window (|d|<4); staging clamp
                // already equals the reference image clamp.
                const int ib = ((fy - row0) * WN + (fx - col0)) << 2;
                const int co[4] = {ib + j2,
                                   ib + CUNITS + j2,
                                   ib + WN * CUNITS + j2,
                                   ib + (WN + 1) * CUNITS + j2};
#pragma unroll
                for (int c = 0; c < 4; ++c) {
                    const uint4v va = tile[co[c]];
                    const uint4v vb = tile[co[c] + 1];
                    const float  cc = cw[c];
                    FMA_MIX_LO(acc[0],  va.x, cc); FMA_MIX_HI(acc[1],  va.x, cc);
                    FMA_MIX_LO(acc[2],  va.y, cc); FMA_MIX_HI(acc[3],  va.y, cc);
                    FMA_MIX_LO(acc[4],  va.z, cc); FMA_MIX_HI(acc[5],  va.z, cc);
                    FMA_MIX_LO(acc[6],  va.w, cc); FMA_MIX_HI(acc[7],  va.w, cc);
                    FMA_MIX_LO(acc[8],  vb.x, cc); FMA_MIX_HI(acc[9],  vb.x, cc);
                    FMA_MIX_LO(acc[10], vb.y, cc); FMA_MIX_HI(acc[11], vb.y, cc);
                    FMA_MIX_LO(acc[12], vb.z, cc); FMA_MIX_HI(acc[13], vb.z, cc);
                    FMA_MIX_LO(acc[14], vb.w, cc); FMA_MIX_HI(acc[15], vb.w, cc);
                }
            } else {
                // rare (P~1e-4): exact f32 global gather, true reference clamps
                const float ax0 = ((uint32_t)fx       < (uint32_t)Wc) ? wx0 : 0.f;
                const float ax1 = ((uint32_t)(fx + 1) < (uint32_t)Wc) ? wx1 : 0.f;
                const float ay0 = ((uint32_t)fy       < (uint32_t)Hc) ? wy0 : 0.f;
                const float ay1 = ((uint32_t)(fy + 1) < (uint32_t)Hc) ? wy1 : 0.f;
                const int xf = min(max(fx,     0), Wc - 1);
                const int xc = min(max(fx + 1, 0), Wc - 1);
                const int yf = min(max(fy,     0), Hc - 1);
                const int yc = min(max(fy + 1, 0), Hc - 1);
                const float ay0k = wk * ay0;
                const float ay1k = wk * ay1;
                const float c00 = ay0k * ax0;
                const float c01 = ay0k * ax1;
                const float c10 = ay1k * ax0;
                const float c11 = ay1k * ax1;
                const float4v* p00 = &gp4[yf * 8192 + xf * 64 + 4 * j];
                const float4v* p01 = &gp4[yf * 8192 + xc * 64 + 4 * j];
                const float4v* p10 = &gp4[yc * 8192 + xf * 64 + 4 * j];
                const float4v* p11 = &gp4[yc * 8192 + xc * 64 + 4 * j];
#pragma unroll
                for (int u4 = 0; u4 < 4; ++u4) {
                    const float4v a = p00[u4], bb = p01[u4];
                    const float4v c = p10[u4], dd = p11[u4];
#pragma unroll
                    for (int e = 0; e < 4; ++e) {
                        float s = acc[u4 * 4 + e];
                        s = fmaf(a[e],  c00, s);
                        s = fmaf(bb[e], c01, s);
                        s = fmaf(c[e],  c10, s);
                        s = fmaf(dd[e], c11, s);
                        acc[u4 * 4 + e] = s;
                    }
                }
            }
        }
    };

    // interior tiles: in-halo corners provably in-image -> masks all 1
    const bool interior = ((uint32_t)(wt - 1) <= 5u) & ((uint32_t)(ht - 1) <= 13u);
    if (interior) kloop(std::integral_constant<bool, false>{});
    else          kloop(std::integral_constant<bool, true>{});

    // channels 16j..16j+15 = float4 units 4j..4j+3 (64 B contiguous)
    float4v* op = (float4v*)((char*)out + (size_t)pg * 128) + 4 * j;
#pragma unroll
    for (int u4 = 0; u4 < 4; ++u4) {
        float4v o = {acc[u4*4], acc[u4*4+1], acc[u4*4+2], acc[u4*4+3]};
        op[u4] = o;
    }
}

extern "C" void kernel_launch(void* const* d_in, const int* in_sizes, int n_in,
                              void* d_out, int out_size, void* d_ws, size_t ws_size,
                              hipStream_t stream) {
    const float* inp = (const float*)d_in[0];
    const float* def = (const float*)d_in[1];
    const float* wts = (const float*)d_in[2];
    float* out = (float*)d_out;

    const int nblocks = Bc * Gc * (Hc / TH) * (Wc / TW);  // 4096
    dcn_fwd<<<nblocks, 256, 0, stream>>>(inp, def, wts, out);
}

// Round 19
// 43.683 us; speedup vs baseline: 1.1888x; 1.1888x over previous
//
#include <hip/hip_runtime.h>
#include <stdint.h>
#include <type_traits>

// DCN forward: B=4, H=128, W=128, G=8, C=32, K=8
// inputs      [B,H,W,G,C]   fp32
// deformables [B,H,W,G,K,2] fp32
// weights     [B,H,W,G,K]   fp32
// out         [B,H,W,G,C]   fp32
//
// R19 = revert to R17 champion (43.36 us). R18's 2-lanes/px doubled bank
// conflicts (4.35M->9.71M: a ds_read_b128 phase spanned 4 pixels) and
// regressed to 51.9. Lane-mapping axis now fully explored: 8/px VALU-bound,
// 4/px optimum, 2/px conflict-bound, 1/px staging-bound.
//  - 8x16 px tile, 512 thr, 4 lanes/px; v_fma_mix_f32 asm (1 inst/channel).
//  - f16 tile, CUNITS=4 (64B cells), WN=25 (odd: phase-partner pixels with
//    dfx+dfy odd land in opposite bank halves).
//  - RH=4 halo (fallback P~1e-4, no wave divergence in practice).
//  - coalesced (cell,unit)-linear staging; interior mask-elision;
//    unclamped-index == staging-clamp equivalence; exact f32 fallback.

#define Bc 4
#define Hc 128
#define Wc 128
#define Gc 8
#define Kc 8
#define TH 8
#define TW 16
#define RH 4
#define WR 16             // window rows = TH + 2*RH
#define WN 25             // window cols (24 used + 1 pad col, ODD for parity)
#define NCELL (WR*WN)     // 400
#define CUNITS 4          // 16B units per cell (64 B, no pad)

typedef float    float4v __attribute__((ext_vector_type(4)));
typedef _Float16 half8v  __attribute__((ext_vector_type(8)));
typedef uint32_t uint4v  __attribute__((ext_vector_type(4)));

union PkU { half8v h; uint4v u; };

// acc += (f16 lo/hi of PK) * C   -- exact f32 fma, f16 converted exactly
#define FMA_MIX_LO(ACC, PK, C) \
    asm("v_fma_mix_f32 %0, %1, %2, %0 op_sel:[0,0,0] op_sel_hi:[1,0,0]" \
        : "+v"(ACC) : "v"(PK), "v"(C))
#define FMA_MIX_HI(ACC, PK, C) \
    asm("v_fma_mix_f32 %0, %1, %2, %0 op_sel:[1,0,0] op_sel_hi:[1,0,0]" \
        : "+v"(ACC) : "v"(PK), "v"(C))

__global__ __launch_bounds__(512, 4) void dcn_fwd(
    const float* __restrict__ inp,
    const float* __restrict__ def,
    const float* __restrict__ wts,
    float* __restrict__ out)
{
    const int tid = threadIdx.x;
    const int j   = tid & 3;       // lane owns channels 8j..8j+7 (one 16B unit)
    const int px  = tid >> 2;      // 0..127 pixel in tile
    const int pw  = px & 15;
    const int ph  = px >> 4;

    // grid: wt(8), ht(16), g(8), b(4)
    const int blk = blockIdx.x;
    const int wt = blk & 7;
    const int ht = (blk >> 3) & 15;
    const int g  = (blk >> 7) & 7;
    const int b  = blk >> 10;

    const int h0 = ht * TH, w0 = wt * TW;
    const int row0 = h0 - RH, col0 = w0 - RH;   // window origin (may be <0)

    // global plane as float4 units: index = y*8192 + x*64 + u
    const float4v* gp4 = (const float4v*)((const char*)inp
        + ((size_t)b << 24) + ((size_t)g << 7));

    __shared__ uint4v tile[NCELL * CUNITS];   // 25600 B

    const int h = h0 + ph;
    const int w = w0 + pw;
    const int pg = ((b * Hc + h) * Wc + w) * Gc + g;

    // per-pixel def/wts (4 lanes load same addr; coalescer merges)
    const float4v d0 = *(const float4v*)(def + (size_t)pg * 16 + 0);
    const float4v d1 = *(const float4v*)(def + (size_t)pg * 16 + 4);
    const float4v d2 = *(const float4v*)(def + (size_t)pg * 16 + 8);
    const float4v d3 = *(const float4v*)(def + (size_t)pg * 16 + 12);
    const float4v q0 = *(const float4v*)(wts + (size_t)pg * 8 + 0);
    const float4v q1 = *(const float4v*)(wts + (size_t)pg * 8 + 4);

    // ---- stage 16x25 cell window as f16 (RTE): linear (cell,u2), coalesced ----
    // 400 cells x 4 units = 1600 writes; 4 rounds of 512 (last partial).
#pragma unroll
    for (int r = 0; r < 4; ++r) {
        const int idx = r * 512 + tid;
        if (idx < NCELL * CUNITS) {
            const int cell = idx >> 2;
            const int u2   = idx & 3;
            const int rr   = (cell * 2622) >> 16;    // exact cell/25, cell<400
            const int cc   = cell - rr * WN;
            const int gr   = min(max(row0 + rr, 0), Hc - 1);
            const int gc   = min(max(col0 + cc, 0), Wc - 1);
            const float4v* src = &gp4[gr * 8192 + gc * 64 + u2 * 2];
            const float4v a = src[0];
            const float4v c = src[1];
            PkU p;
            p.h = (half8v){(_Float16)a.x, (_Float16)a.y, (_Float16)a.z, (_Float16)a.w,
                           (_Float16)c.x, (_Float16)c.y, (_Float16)c.z, (_Float16)c.w};
            tile[(cell << 2) + u2] = p.u;
        }
    }
    __syncthreads();

    const float dxs[8] = {d0.x, d0.z, d1.x, d1.z, d2.x, d2.z, d3.x, d3.z};
    const float dys[8] = {d0.y, d0.w, d1.y, d1.w, d2.y, d2.w, d3.y, d3.w};
    const float wks[8] = {q0.x, q0.y, q0.z, q0.w, q1.x, q1.y, q1.z, q1.w};

    const float wf = (float)w;
    const float hf = (float)h;

    float acc[8];
#pragma unroll
    for (int i = 0; i < 8; ++i) acc[i] = 0.f;

    auto kloop = [&](auto masked_t) {
        constexpr bool MASKED = decltype(masked_t)::value;
#pragma unroll
        for (int k = 0; k < Kc; ++k) {
            const float dx = dxs[k];
            const float dy = dys[k];
            const float wk = wks[k];

            const float x = dx + wf;
            const float y = dy + hf;

            // truncation toward zero, matching .astype(int32)
            const int fx = (int)x;
            const int fy = (int)y;

            const float wx1 = x - (float)fx;   // exact
            const float wy1 = y - (float)fy;
            const float wx0 = 1.0f - wx1;      // == cxf - x
            const float wy0 = 1.0f - wy1;

            const bool inh = (fabsf(dx) < 4.0f) & (fabsf(dy) < 4.0f);
            if (__builtin_expect(inh, 1)) {
                float ax0 = wx0, ax1 = wx1, ay0 = wy0, ay1 = wy1;
                if constexpr (MASKED) {
                    ax0 = ((uint32_t)fx       < (uint32_t)Wc) ? wx0 : 0.f;
                    ax1 = ((uint32_t)(fx + 1) < (uint32_t)Wc) ? wx1 : 0.f;
                    ay0 = ((uint32_t)fy       < (uint32_t)Hc) ? wy0 : 0.f;
                    ay1 = ((uint32_t)(fy + 1) < (uint32_t)Hc) ? wy1 : 0.f;
                }
                const float ay0k = wk * ay0;
                const float ay1k = wk * ay1;
                const float c00 = ay0k * ax0;
                const float c01 = ay0k * ax1;
                const float c10 = ay1k * ax0;
                const float c11 = ay1k * ax1;

                // unclamped fx,fy valid in-window (|d|<4); staging clamp
                // already equals the reference image clamp.
                const int iu = (((fy - row0) * WN + (fx - col0)) << 2) + j;
                const uint4v v00 = tile[iu];                           // (x  ,y  )
                const uint4v v01 = tile[iu + CUNITS];                  // (x+1,y  )
                const uint4v v10 = tile[iu + WN * CUNITS];             // (x  ,y+1)
                const uint4v v11 = tile[iu + (WN + 1) * CUNITS];       // (x+1,y+1)

                FMA_MIX_LO(acc[0], v00.x, c00); FMA_MIX_HI(acc[1], v00.x, c00);
                FMA_MIX_LO(acc[2], v00.y, c00); FMA_MIX_HI(acc[3], v00.y, c00);
                FMA_MIX_LO(acc[4], v00.z, c00); FMA_MIX_HI(acc[5], v00.z, c00);
                FMA_MIX_LO(acc[6], v00.w, c00); FMA_MIX_HI(acc[7], v00.w, c00);

                FMA_MIX_LO(acc[0], v01.x, c01); FMA_MIX_HI(acc[1], v01.x, c01);
                FMA_MIX_LO(acc[2], v01.y, c01); FMA_MIX_HI(acc[3], v01.y, c01);
                FMA_MIX_LO(acc[4], v01.z, c01); FMA_MIX_HI(acc[5], v01.z, c01);
                FMA_MIX_LO(acc[6], v01.w, c01); FMA_MIX_HI(acc[7], v01.w, c01);

                FMA_MIX_LO(acc[0], v10.x, c10); FMA_MIX_HI(acc[1], v10.x, c10);
                FMA_MIX_LO(acc[2], v10.y, c10); FMA_MIX_HI(acc[3], v10.y, c10);
                FMA_MIX_LO(acc[4], v10.z, c10); FMA_MIX_HI(acc[5], v10.z, c10);
                FMA_MIX_LO(acc[6], v10.w, c10); FMA_MIX_HI(acc[7], v10.w, c10);

                FMA_MIX_LO(acc[0], v11.x, c11); FMA_MIX_HI(acc[1], v11.x, c11);
                FMA_MIX_LO(acc[2], v11.y, c11); FMA_MIX_HI(acc[3], v11.y, c11);
                FMA_MIX_LO(acc[4], v11.z, c11); FMA_MIX_HI(acc[5], v11.z, c11);
                FMA_MIX_LO(acc[6], v11.w, c11); FMA_MIX_HI(acc[7], v11.w, c11);
            } else {
                // rare (P~1e-4): exact f32 global gather, true reference clamps
                const float ax0 = ((uint32_t)fx       < (uint32_t)Wc) ? wx0 : 0.f;
                const float ax1 = ((uint32_t)(fx + 1) < (uint32_t)Wc) ? wx1 : 0.f;
                const float ay0 = ((uint32_t)fy       < (uint32_t)Hc) ? wy0 : 0.f;
                const float ay1 = ((uint32_t)(fy + 1) < (uint32_t)Hc) ? wy1 : 0.f;
                const int xf = min(max(fx,     0), Wc - 1);
                const int xc = min(max(fx + 1, 0), Wc - 1);
                const int yf = min(max(fy,     0), Hc - 1);
                const int yc = min(max(fy + 1, 0), Hc - 1);
                const float ay0k = wk * ay0;
                const float ay1k = wk * ay1;
                const float c00 = ay0k * ax0;
                const float c01 = ay0k * ax1;
                const float c10 = ay1k * ax0;
                const float c11 = ay1k * ax1;
                const float4v* p00 = &gp4[yf * 8192 + xf * 64 + 2 * j];
                const float4v* p01 = &gp4[yf * 8192 + xc * 64 + 2 * j];
                const float4v* p10 = &gp4[yc * 8192 + xf * 64 + 2 * j];
                const float4v* p11 = &gp4[yc * 8192 + xc * 64 + 2 * j];
#pragma unroll
                for (int u2 = 0; u2 < 2; ++u2) {
                    const float4v a = p00[u2], bb = p01[u2];
                    const float4v c = p10[u2], dd = p11[u2];
#pragma unroll
                    for (int e = 0; e < 4; ++e) {
                        float s = acc[u2 * 4 + e];
                        s = fmaf(a[e],  c00, s);
                        s = fmaf(bb[e], c01, s);
                        s = fmaf(c[e],  c10, s);
                        s = fmaf(dd[e], c11, s);
                        acc[u2 * 4 + e] = s;
                    }
                }
            }
        }
    };

    // interior tiles: in-halo corners provably in-image -> masks all 1
    const bool interior = ((uint32_t)(wt - 1) <= 5u) & ((uint32_t)(ht - 1) <= 13u);
    if (interior) kloop(std::integral_constant<bool, false>{});
    else          kloop(std::integral_constant<bool, true>{});

    // channels 8j..8j+7 = float4 units 2j, 2j+1 (32 B contiguous)
    float4v* op = (float4v*)((char*)out + (size_t)pg * 128) + 2 * j;
    float4v o0 = {acc[0], acc[1], acc[2], acc[3]};
    float4v o1 = {acc[4], acc[5], acc[6], acc[7]};
    op[0] = o0;
    op[1] = o1;
}

extern "C" void kernel_launch(void* const* d_in, const int* in_sizes, int n_in,
                              void* d_out, int out_size, void* d_ws, size_t ws_size,
                              hipStream_t stream) {
    const float* inp = (const float*)d_in[0];
    const float* def = (const float*)d_in[1];
    const float* wts = (const float*)d_in[2];
    float* out = (float*)d_out;

    const int nblocks = Bc * Gc * (Hc / TH) * (Wc / TW);  // 4096
    dcn_fwd<<<nblocks, 512, 0, stream>>>(inp, def, wts, out);
}

// Round 21
// 42.502 us; speedup vs baseline: 1.2218x; 1.0278x over previous
//
#include <hip/hip_runtime.h>
#include <stdint.h>
#include <type_traits>

// DCN forward: B=4, H=128, W=128, G=8, C=32, K=8
// inputs      [B,H,W,G,C]   fp32
// deformables [B,H,W,G,K,2] fp32
// weights     [B,H,W,G,K]   fp32
// out         [B,H,W,G,C]   fp32
//
// R21 = R20 with the cvt_pkrtz type fixed (builtin returns __fp16 vec2, not
// _Float16 vec2). Theory unchanged: in-halo FMA block switched from 32x
// v_fma_mix_f32 to 16x v_pk_fma_f16 + 4x cvt_pkrtz packs (~24% k-loop VALU
// cut on the largest pipe). f16 accumulation budget: ~0.25 worst-case
// running-sum + 0.125 tile error < 0.5775 threshold. Rare f32 fallback
// accumulates exactly in a separate set, merged in the epilogue.
// Everything else verbatim R17: 8x16 px tile, 512 thr, 4 lanes/px, f16 tile
// CUNITS=4/WN=25, RH=4, coalesced staging, interior mask-elision,
// unclamped-index == staging-clamp equivalence.

#define Bc 4
#define Hc 128
#define Wc 128
#define Gc 8
#define Kc 8
#define TH 8
#define TW 16
#define RH 4
#define WR 16             // window rows = TH + 2*RH
#define WN 25             // window cols (24 used + 1 pad col, ODD for parity)
#define NCELL (WR*WN)     // 400
#define CUNITS 4          // 16B units per cell (64 B, no pad)

typedef float    float4v __attribute__((ext_vector_type(4)));
typedef _Float16 half8v  __attribute__((ext_vector_type(8)));
typedef __fp16   fp16x2  __attribute__((ext_vector_type(2)));
typedef uint32_t uint4v  __attribute__((ext_vector_type(4)));

union PkU { half8v h; uint4v u; };
union H2U { fp16x2 h; uint32_t u; };

// ACC(2xf16) += V(2xf16) * C(2xf16)  -- fused, single rounding per half
#define PK_FMA(ACC, V, C) \
    asm("v_pk_fma_f16 %0, %1, %2, %0" : "+v"(ACC) : "v"(V), "v"(C))

__global__ __launch_bounds__(512, 4) void dcn_fwd(
    const float* __restrict__ inp,
    const float* __restrict__ def,
    const float* __restrict__ wts,
    float* __restrict__ out)
{
    const int tid = threadIdx.x;
    const int j   = tid & 3;       // lane owns channels 8j..8j+7 (one 16B unit)
    const int px  = tid >> 2;      // 0..127 pixel in tile
    const int pw  = px & 15;
    const int ph  = px >> 4;

    // grid: wt(8), ht(16), g(8), b(4)
    const int blk = blockIdx.x;
    const int wt = blk & 7;
    const int ht = (blk >> 3) & 15;
    const int g  = (blk >> 7) & 7;
    const int b  = blk >> 10;

    const int h0 = ht * TH, w0 = wt * TW;
    const int row0 = h0 - RH, col0 = w0 - RH;   // window origin (may be <0)

    // global plane as float4 units: index = y*8192 + x*64 + u
    const float4v* gp4 = (const float4v*)((const char*)inp
        + ((size_t)b << 24) + ((size_t)g << 7));

    __shared__ uint4v tile[NCELL * CUNITS];   // 25600 B

    const int h = h0 + ph;
    const int w = w0 + pw;
    const int pg = ((b * Hc + h) * Wc + w) * Gc + g;

    // per-pixel def/wts (4 lanes load same addr; coalescer merges)
    const float4v d0 = *(const float4v*)(def + (size_t)pg * 16 + 0);
    const float4v d1 = *(const float4v*)(def + (size_t)pg * 16 + 4);
    const float4v d2 = *(const float4v*)(def + (size_t)pg * 16 + 8);
    const float4v d3 = *(const float4v*)(def + (size_t)pg * 16 + 12);
    const float4v q0 = *(const float4v*)(wts + (size_t)pg * 8 + 0);
    const float4v q1 = *(const float4v*)(wts + (size_t)pg * 8 + 4);

    // ---- stage 16x25 cell window as f16 (RTE): linear (cell,u2), coalesced ----
#pragma unroll
    for (int r = 0; r < 4; ++r) {
        const int idx = r * 512 + tid;
        if (idx < NCELL * CUNITS) {
            const int cell = idx >> 2;
            const int u2   = idx & 3;
            const int rr   = (cell * 2622) >> 16;    // exact cell/25, cell<400
            const int cc   = cell - rr * WN;
            const int gr   = min(max(row0 + rr, 0), Hc - 1);
            const int gc   = min(max(col0 + cc, 0), Wc - 1);
            const float4v* src = &gp4[gr * 8192 + gc * 64 + u2 * 2];
            const float4v a = src[0];
            const float4v c = src[1];
            PkU p;
            p.h = (half8v){(_Float16)a.x, (_Float16)a.y, (_Float16)a.z, (_Float16)a.w,
                           (_Float16)c.x, (_Float16)c.y, (_Float16)c.z, (_Float16)c.w};
            tile[(cell << 2) + u2] = p.u;
        }
    }
    __syncthreads();

    const float dxs[8] = {d0.x, d0.z, d1.x, d1.z, d2.x, d2.z, d3.x, d3.z};
    const float dys[8] = {d0.y, d0.w, d1.y, d1.w, d2.y, d2.w, d3.y, d3.w};
    const float wks[8] = {q0.x, q0.y, q0.z, q0.w, q1.x, q1.y, q1.z, q1.w};

    const float wf = (float)w;
    const float hf = (float)h;

    // f16 pair accumulators (channels 2i, 2i+1) + exact f32 set for fallback
    uint32_t acch[4] = {0u, 0u, 0u, 0u};
    float accf[8];
#pragma unroll
    for (int i = 0; i < 8; ++i) accf[i] = 0.f;

    auto kloop = [&](auto masked_t) {
        constexpr bool MASKED = decltype(masked_t)::value;
#pragma unroll
        for (int k = 0; k < Kc; ++k) {
            const float dx = dxs[k];
            const float dy = dys[k];
            const float wk = wks[k];

            const float x = dx + wf;
            const float y = dy + hf;

            // truncation toward zero, matching .astype(int32)
            const int fx = (int)x;
            const int fy = (int)y;

            const float wx1 = x - (float)fx;   // exact
            const float wy1 = y - (float)fy;
            const float wx0 = 1.0f - wx1;      // == cxf - x
            const float wy0 = 1.0f - wy1;

            const bool inh = (fabsf(dx) < 4.0f) & (fabsf(dy) < 4.0f);
            if (__builtin_expect(inh, 1)) {
                float ax0 = wx0, ax1 = wx1, ay0 = wy0, ay1 = wy1;
                if constexpr (MASKED) {
                    ax0 = ((uint32_t)fx       < (uint32_t)Wc) ? wx0 : 0.f;
                    ax1 = ((uint32_t)(fx + 1) < (uint32_t)Wc) ? wx1 : 0.f;
                    ay0 = ((uint32_t)fy       < (uint32_t)Hc) ? wy0 : 0.f;
                    ay1 = ((uint32_t)(fy + 1) < (uint32_t)Hc) ? wy1 : 0.f;
                }
                const float ay0k = wk * ay0;
                const float ay1k = wk * ay1;
                const float c00 = ay0k * ax0;
                const float c01 = ay0k * ax1;
                const float c10 = ay1k * ax0;
                const float c11 = ay1k * ax1;

                // packed duplicate coefficients (RTZ, rel err <= 2^-10)
                H2U u00, u01, u10, u11;
                u00.h = __builtin_amdgcn_cvt_pkrtz(c00, c00);
                u01.h = __builtin_amdgcn_cvt_pkrtz(c01, c01);
                u10.h = __builtin_amdgcn_cvt_pkrtz(c10, c10);
                u11.h = __builtin_amdgcn_cvt_pkrtz(c11, c11);

                // unclamped fx,fy valid in-window (|d|<4); staging clamp
                // already equals the reference image clamp.
                const int iu = (((fy - row0) * WN + (fx - col0)) << 2) + j;
                const uint4v v00 = tile[iu];                           // (x  ,y  )
                const uint4v v01 = tile[iu + CUNITS];                  // (x+1,y  )
                const uint4v v10 = tile[iu + WN * CUNITS];             // (x  ,y+1)
                const uint4v v11 = tile[iu + (WN + 1) * CUNITS];       // (x+1,y+1)

                PK_FMA(acch[0], v00.x, u00.u); PK_FMA(acch[1], v00.y, u00.u);
                PK_FMA(acch[2], v00.z, u00.u); PK_FMA(acch[3], v00.w, u00.u);

                PK_FMA(acch[0], v01.x, u01.u); PK_FMA(acch[1], v01.y, u01.u);
                PK_FMA(acch[2], v01.z, u01.u); PK_FMA(acch[3], v01.w, u01.u);

                PK_FMA(acch[0], v10.x, u10.u); PK_FMA(acch[1], v10.y, u10.u);
                PK_FMA(acch[2], v10.z, u10.u); PK_FMA(acch[3], v10.w, u10.u);

                PK_FMA(acch[0], v11.x, u11.u); PK_FMA(acch[1], v11.y, u11.u);
                PK_FMA(acch[2], v11.z, u11.u); PK_FMA(acch[3], v11.w, u11.u);
            } else {
                // rare (P~1e-4): exact f32 global gather, true reference clamps
                const float ax0 = ((uint32_t)fx       < (uint32_t)Wc) ? wx0 : 0.f;
                const float ax1 = ((uint32_t)(fx + 1) < (uint32_t)Wc) ? wx1 : 0.f;
                const float ay0 = ((uint32_t)fy       < (uint32_t)Hc) ? wy0 : 0.f;
                const float ay1 = ((uint32_t)(fy + 1) < (uint32_t)Hc) ? wy1 : 0.f;
                const int xf = min(max(fx,     0), Wc - 1);
                const int xc = min(max(fx + 1, 0), Wc - 1);
                const int yf = min(max(fy,     0), Hc - 1);
                const int yc = min(max(fy + 1, 0), Hc - 1);
                const float ay0k = wk * ay0;
                const float ay1k = wk * ay1;
                const float c00 = ay0k * ax0;
                const float c01 = ay0k * ax1;
                const float c10 = ay1k * ax0;
                const float c11 = ay1k * ax1;
                const float4v* p00 = &gp4[yf * 8192 + xf * 64 + 2 * j];
                const float4v* p01 = &gp4[yf * 8192 + xc * 64 + 2 * j];
                const float4v* p10 = &gp4[yc * 8192 + xf * 64 + 2 * j];
                const float4v* p11 = &gp4[yc * 8192 + xc * 64 + 2 * j];
#pragma unroll
                for (int u2 = 0; u2 < 2; ++u2) {
                    const float4v a = p00[u2], bb = p01[u2];
                    const float4v c = p10[u2], dd = p11[u2];
#pragma unroll
                    for (int e = 0; e < 4; ++e) {
                        float s = accf[u2 * 4 + e];
                        s = fmaf(a[e],  c00, s);
                        s = fmaf(bb[e], c01, s);
                        s = fmaf(c[e],  c10, s);
                        s = fmaf(dd[e], c11, s);
                        accf[u2 * 4 + e] = s;
                    }
                }
            }
        }
    };

    // interior tiles: in-halo corners provably in-image -> masks all 1
    const bool interior = ((uint32_t)(wt - 1) <= 5u) & ((uint32_t)(ht - 1) <= 13u);
    if (interior) kloop(std::integral_constant<bool, false>{});
    else          kloop(std::integral_constant<bool, true>{});

    // epilogue: merge f16 accumulators (exact f16->f32 convert) with f32 set
#pragma unroll
    for (int i = 0; i < 4; ++i) {
        H2U t; t.u = acch[i];
        accf[2 * i]     += (float)t.h.x;
        accf[2 * i + 1] += (float)t.h.y;
    }

    // channels 8j..8j+7 = float4 units 2j, 2j+1 (32 B contiguous)
    float4v* op = (float4v*)((char*)out + (size_t)pg * 128) + 2 * j;
    float4v o0 = {accf[0], accf[1], accf[2], accf[3]};
    float4v o1 = {accf[4], accf[5], accf[6], accf[7]};
    op[0] = o0;
    op[1] = o1;
}

extern "C" void kernel_launch(void* const* d_in, const int* in_sizes, int n_in,
                              void* d_out, int out_size, void* d_ws, size_t ws_size,
                              hipStream_t stream) {
    const float* inp = (const float*)d_in[0];
    const float* def = (const float*)d_in[1];
    const float* wts = (const float*)d_in[2];
    float* out = (float*)d_out;

    const int nblocks = Bc * Gc * (Hc / TH) * (Wc / TW);  // 4096
    dcn_fwd<<<nblocks, 512, 0, stream>>>(inp, def, wts, out);
}